// Round 4
// baseline (119.888 us; speedup 1.0000x reference)
//
#include <hip/hip_runtime.h>
#include <cmath>

#define SS 48
#define S3 110592
#define NB 8
#define CIN 4
#define COUT 4
#define HID 128
#define XT 27
#define NP 20
#define BATCH 4
#define LSTR 40           // shorts per halo voxel (80 B padded row)

typedef __attribute__((ext_vector_type(8))) short short8;
typedef __attribute__((ext_vector_type(4))) float f32x4;

struct Tables {
    int   pid[64];   // [bj*8+bk] -> path index
    float sgn[64];   // [bj*8+bk] -> +-1
};

__device__ __forceinline__ unsigned short bf16_rne(float f) {
    union { float f; unsigned u; } c; c.f = f;
    unsigned r = c.u + 0x7FFF + ((c.u >> 16) & 1);
    return (unsigned short)(r >> 16);
}

__device__ __forceinline__ float gelu_tanh(float v) {
    const float c = 0.7978845608028654f;   // sqrt(2/pi)
    float u = c * (v + 0.044715f * v * v * v);
    return 0.5f * v * (1.0f + tanhf(u));
}

// ---------- Stage 1: masked global pooling -> cond sums (B, NB) -------------
__global__ __launch_bounds__(256)
void cond_kernel(const float* __restrict__ x, float* __restrict__ cond) {
    int b = blockIdx.y;
    int t = threadIdx.x;
    __shared__ float sacc[8];
    if (t < 8) sacc[t] = 0.0f;
    __syncthreads();
    float acc[8];
#pragma unroll
    for (int n = 0; n < 8; ++n) acc[n] = 0.0f;
#pragma unroll
    for (int k = 0; k < 8; ++k) {
        int v = blockIdx.x * 256 + t + k * 13824;
        int z = v / 2304, rem = v % 2304, y = rem / 48, xx = rem % 48;
        int dx = 2 * xx - 47, dy = 2 * y - 47, dz = 2 * z - 47;
        if (dx * dx + dy * dy + dz * dz <= 2209) {
#pragma unroll
            for (int i = 0; i < 4; ++i) {
                const f32x4* p = (const f32x4*)(x + (((size_t)(b * 4 + i)) * S3 + v) * 8);
                f32x4 a = p[0], c4 = p[1];
                acc[0] += a[0];  acc[1] += a[1];  acc[2] += a[2];  acc[3] += a[3];
                acc[4] += c4[0]; acc[5] += c4[1]; acc[6] += c4[2]; acc[7] += c4[3];
            }
        }
    }
#pragma unroll
    for (int n = 0; n < 8; ++n) {
        float a = acc[n];
        for (int off = 32; off; off >>= 1) a += __shfl_down(a, off);
        if ((t & 63) == 0) atomicAdd(&sacc[n], a);
    }
    __syncthreads();
    if (t < 8) atomicAdd(&cond[b * 8 + t], sacc[t]);
}

// ---------- Stage 2: fused kernel-network MLP + Cayley assembly -------------
// one block per (b, tap); 128 threads; emits bf16 W tile [m=o*8+bk][c=i*8+bj]
__global__ __launch_bounds__(128)
void mlpw_kernel(const float* __restrict__ cond,
                 const float* __restrict__ w0, const float* __restrict__ b0,
                 const float* __restrict__ w1, const float* __restrict__ b1,
                 const float* __restrict__ w2, const float* __restrict__ b2,
                 unsigned short* __restrict__ wb, float inv_norm, Tables tb) {
    int bx = blockIdx.x;
    int b = bx / XT;
    int tap = bx % XT;
    int t = threadIdx.x;
    __shared__ float feat[2 * NB];
    __shared__ float h1[HID];
    __shared__ float h2[HID];
    __shared__ float wrow[320];
    if (t < 2 * NB) {
        float v = 0.0f;
        if (t < NB) {
            if (t == 1) v = (float)(tap / 9) - 1.0f;
            else if (t == 2) v = (float)((tap / 3) % 3) - 1.0f;
            else if (t == 3) v = (float)(tap % 3) - 1.0f;
        } else {
            v = cond[b * NB + (t - NB)] * inv_norm;
        }
        feat[t] = v;
    }
    __syncthreads();
    float s = b0[t];
#pragma unroll
    for (int k = 0; k < 2 * NB; ++k) s += feat[k] * w0[k * HID + t];
    h1[t] = gelu_tanh(s);
    __syncthreads();
    s = b1[t];
    for (int k = 0; k < HID; ++k) s += h1[k] * w1[k * HID + t];
    h2[t] = gelu_tanh(s);
    __syncthreads();
    {
        float o0 = b2[t], o1 = b2[t + 128];
        float o2 = (t < 64) ? b2[t + 256] : 0.0f;
        for (int k = 0; k < HID; ++k) {
            float h = h2[k];
            const float* wr = w2 + (size_t)k * 320;
            o0 += h * wr[t];
            o1 += h * wr[t + 128];
            if (t < 64) o2 += h * wr[t + 256];
        }
        wrow[t] = o0;
        wrow[t + 128] = o1;
        if (t < 64) wrow[t + 256] = o2;
    }
    __syncthreads();
    // assemble: thread t -> m = t>>2 (o*8+bk), 8 c values at cq = t&3
    int m = t >> 2, cq = t & 3;
    int o = m >> 3, bk = m & 7;
    short8 sv;
#pragma unroll
    for (int e = 0; e < 8; ++e) {
        int c = cq * 8 + e;
        int i = c >> 3, bj = c & 7, jk = bj * 8 + bk;
        sv[e] = (short)bf16_rne(tb.sgn[jk] * wrow[o * 80 + i * 20 + tb.pid[jk]]);
    }
    *(short8*)(wb + ((size_t)bx * 32 + m) * 32 + cq * 8) = sv;
}

// ---------- Stage 3: MFMA grouped conv, fp32->bf16 LDS staging --------------
// block: 8x8x4 output tile, 4 waves (one z-slice each); halo 10x10x6 in LDS.
// W hoisted to registers per kz-phase (9 taps x 2 halves = 72 VGPR).
__global__ __launch_bounds__(256, 3)
void conv_lds(const float* __restrict__ x, const unsigned short* __restrict__ wb,
              const float* __restrict__ bias, float* __restrict__ out) {
    __shared__ __align__(16) short lds[600 * LSTR];   // 48000 B
    int b  = blockIdx.y;
    int bx = blockIdx.x;
    int tx = bx % 6, ty = (bx / 6) % 6, tz = bx / 36;
    int X0 = tx * 8, Y0 = ty * 8, Z0 = tz * 4;        // output-tile origin
    int tid = threadIdx.x;

    // staging: 600 halo voxels x 4 i-slices; fp32 read + cvt + ds_write
    for (int c = tid; c < 2400; c += 256) {
        int h = c >> 2, i = c & 3;
        int hz = h / 100, rem = h % 100, hy = rem / 10, hx = rem % 10;
        int z = Z0 + hz - 1, y = Y0 + hy - 1, xx = X0 + hx - 1;
        short8 sv;
        if ((unsigned)z < 48u && (unsigned)y < 48u && (unsigned)xx < 48u) {
            int v = (z * 48 + y) * 48 + xx;
            const f32x4* p = (const f32x4*)(x + (((size_t)(b * 4 + i)) * S3 + v) * 8);
            f32x4 a = p[0], c4 = p[1];
#pragma unroll
            for (int e = 0; e < 4; ++e) sv[e] = (short)bf16_rne(a[e]);
#pragma unroll
            for (int e = 0; e < 4; ++e) sv[4 + e] = (short)bf16_rne(c4[e]);
        } else {
#pragma unroll
            for (int e = 0; e < 8; ++e) sv[e] = 0;
        }
        *(short8*)(&lds[h * LSTR + i * 8]) = sv;
    }
    __syncthreads();

    int lane = tid & 63, wave = tid >> 6;
    int col = lane & 15, kl = lane >> 4;
    const short* lbase = &lds[(wave * 100 + (col >> 3) * 10 + (col & 7)) * LSTR + kl * 8];
    const unsigned short* wbw = wb + (((size_t)b * XT) * 32 + col) * 32 + kl * 8;

    f32x4 acc[2][4];
#pragma unroll
    for (int mh = 0; mh < 2; ++mh)
#pragma unroll
        for (int r = 0; r < 4; ++r)
#pragma unroll
            for (int e = 0; e < 4; ++e) acc[mh][r][e] = 0.0f;

#pragma unroll
    for (int kz = 0; kz < 3; ++kz) {
        // hoist this z-slab's 9 taps of W into registers (load burst)
        short8 aw0[9], aw1[9];
#pragma unroll
        for (int t9 = 0; t9 < 9; ++t9) {
            aw0[t9] = *(const short8*)(wbw + (size_t)(kz * 9 + t9) * 1024);
            aw1[t9] = *(const short8*)(wbw + (size_t)(kz * 9 + t9) * 1024 + 512);
        }
#pragma unroll
        for (int ky = 0; ky < 3; ++ky)
#pragma unroll
            for (int kx = 0; kx < 3; ++kx) {
                const int t9 = ky * 3 + kx;
                const int toff = (kz * 100 + ky * 10 + kx) * LSTR;
#pragma unroll
                for (int r = 0; r < 4; ++r) {
                    short8 bf = *(const short8*)(lbase + toff + r * (20 * LSTR));
                    acc[0][r] = __builtin_amdgcn_mfma_f32_16x16x32_bf16(aw0[t9], bf, acc[0][r], 0, 0, 0);
                    acc[1][r] = __builtin_amdgcn_mfma_f32_16x16x32_bf16(aw1[t9], bf, acc[1][r], 0, 0, 0);
                }
            }
    }

    int xc = X0 + (col & 7);
    int z  = Z0 + wave;
#pragma unroll
    for (int mh = 0; mh < 2; ++mh) {
        int m0 = kl * 4 + mh * 16;
        int o = m0 >> 3, bk0 = m0 & 7;
        float bi = (bk0 == 0) ? bias[o] : 0.0f;
#pragma unroll
        for (int r = 0; r < 4; ++r) {
            int y = Y0 + (col >> 3) + 2 * r;
            int vox = (z * 48 + y) * 48 + xc;
            f32x4 v = acc[mh][r];
            v[0] += bi;
            *(f32x4*)(out + (((size_t)(b * 4 + o)) * S3 + vox) * 8 + bk0) = v;
        }
    }
}

// ---------------- host ------------------------------------------------------
static inline int pc_host(int v) { return __builtin_popcount(v); }

extern "C" void kernel_launch(void* const* d_in, const int* in_sizes, int n_in,
                              void* d_out, int out_size, void* d_ws, size_t ws_size,
                              hipStream_t stream) {
    const float* x    = (const float*)d_in[0];
    const float* w0   = (const float*)d_in[1];
    const float* b0   = (const float*)d_in[2];
    const float* w1   = (const float*)d_in[3];
    const float* b1   = (const float*)d_in[4];
    const float* w2   = (const float*)d_in[5];
    const float* b2   = (const float*)d_in[6];
    const float* bias = (const float*)d_in[7];
    float* out = (float*)d_out;

    float* ws   = (float*)d_ws;
    float* cond = ws;                              // 32 floats
    unsigned short* wbb = (unsigned short*)(ws + 64);  // bf16 W, 110592 shorts

    // circular-mask voxel count (exact integer arithmetic)
    int cnt = 0;
    for (int z = 0; z < SS; ++z) {
        int dz = 2 * z - 47;
        for (int y = 0; y < SS; ++y) {
            int dy = 2 * y - 47;
            for (int xx = 0; xx < SS; ++xx) {
                int dx = 2 * xx - 47;
                if (dx * dx + dy * dy + dz * dz <= 2209) ++cnt;
            }
        }
    }
    float inv_norm = 1.0f / ((float)cnt * (float)CIN);

    // Cayley sign/path tables
    int pidtab[4][4][4];
    {
        bool ex[4][4][4] = {};
        for (int A = 0; A < 8; ++A)
            for (int B = 0; B < 8; ++B)
                ex[pc_host(A)][pc_host(B)][pc_host(A ^ B)] = true;
        int p = 0;
        for (int gi = 0; gi < 4; ++gi)
            for (int gj = 0; gj < 4; ++gj)
                for (int gk = 0; gk < 4; ++gk)
                    pidtab[gi][gj][gk] = ex[gi][gj][gk] ? p++ : -1;
    }
    static const int blades[8] = {0, 1, 2, 4, 3, 5, 6, 7};  // sorted by (grade, bitmask)
    Tables tb;
    for (int bj = 0; bj < 8; ++bj) {
        for (int bk = 0; bk < 8; ++bk) {
            int bmj = blades[bj], bmk = blades[bk];
            int bma = bmj ^ bmk;
            int sgn = 1, t = bma >> 1;
            while (t) {
                if (pc_host(t & bmj) & 1) sgn = -sgn;
                t >>= 1;
            }
            tb.sgn[bj * 8 + bk] = (float)sgn;
            tb.pid[bj * 8 + bk] = pidtab[pc_host(bma)][pc_host(bmj)][pc_host(bmk)];
        }
    }

    hipMemsetAsync(cond, 0, 32 * sizeof(float), stream);
    cond_kernel<<<dim3(54, BATCH), dim3(256), 0, stream>>>(x, cond);
    mlpw_kernel<<<dim3(BATCH * XT), dim3(HID), 0, stream>>>(cond, w0, b0, w1, b1, w2, b2,
                                                            wbb, inv_norm, tb);
    conv_lds<<<dim3(432, BATCH), dim3(256), 0, stream>>>(x, wbb, bias, out);
}

// Round 5
// 114.560 us; speedup vs baseline: 1.0465x; 1.0465x over previous
//
#include <hip/hip_runtime.h>
#include <cmath>

#define SS 48
#define S3 110592
#define NB 8
#define CIN 4
#define COUT 4
#define HID 128
#define XT 27
#define NP 20
#define BATCH 4
#define PD 50
#define PD2 2500
#define PD3 125000
#define SLAB 4816         // shorts per kl-slab (9632 B; ≡ 8 dwords mod 32 banks)

typedef __attribute__((ext_vector_type(8))) short short8;
typedef __attribute__((ext_vector_type(4))) float f32x4;

struct Tables {
    int   pid[64];   // [bj*8+bk] -> path index
    float sgn[64];   // [bj*8+bk] -> +-1
};

__device__ __forceinline__ unsigned short bf16_rne(float f) {
    union { float f; unsigned u; } c; c.f = f;
    unsigned r = c.u + 0x7FFF + ((c.u >> 16) & 1);
    return (unsigned short)(r >> 16);
}

__device__ __forceinline__ float gelu_tanh(float v) {
    const float c = 0.7978845608028654f;   // sqrt(2/pi)
    float u = c * (v + 0.044715f * v * v * v);
    return 0.5f * v * (1.0f + tanhf(u));
}

// ---------- Stage 1: pack x -> padded bf16 [b][pz][py][px][c] + cond partials
__global__ __launch_bounds__(256)
void pack_cond_kernel(const float* __restrict__ x, unsigned short* __restrict__ xb,
                      float* __restrict__ partial) {
    int b  = blockIdx.y;
    int pv = blockIdx.x * 256 + threadIdx.x;
    __shared__ float sacc[8];
    if (threadIdx.x < 8) sacc[threadIdx.x] = 0.0f;
    __syncthreads();
    float acc[8];
#pragma unroll
    for (int n = 0; n < 8; ++n) acc[n] = 0.0f;
    if (pv < PD3) {
        int zp = pv / PD2, rem = pv % PD2, yp = rem / PD, xp = rem % PD;
        int z = zp - 1, y = yp - 1, xx = xp - 1;
        unsigned short ob[32];
        bool interior = (unsigned)z < 48u && (unsigned)y < 48u && (unsigned)xx < 48u;
        if (interior) {
            int v = (z * 48 + y) * 48 + xx;
            float vals[32];
#pragma unroll
            for (int i = 0; i < 4; ++i) {
                const f32x4* p = (const f32x4*)(x + (((size_t)(b * 4 + i)) * S3 + v) * 8);
                f32x4 a = p[0], c4 = p[1];
                vals[i * 8 + 0] = a[0];  vals[i * 8 + 1] = a[1];
                vals[i * 8 + 2] = a[2];  vals[i * 8 + 3] = a[3];
                vals[i * 8 + 4] = c4[0]; vals[i * 8 + 5] = c4[1];
                vals[i * 8 + 6] = c4[2]; vals[i * 8 + 7] = c4[3];
            }
            int dx = 2 * xx - 47, dy = 2 * y - 47, dz = 2 * z - 47;
            if (dx * dx + dy * dy + dz * dz <= 2209) {
#pragma unroll
                for (int n = 0; n < 8; ++n)
                    acc[n] = vals[n] + vals[8 + n] + vals[16 + n] + vals[24 + n];
            }
#pragma unroll
            for (int k = 0; k < 32; ++k) ob[k] = bf16_rne(vals[k]);
        } else {
#pragma unroll
            for (int k = 0; k < 32; ++k) ob[k] = 0;
        }
        short8* dst = (short8*)(xb + ((size_t)b * PD3 + pv) * 32);
#pragma unroll
        for (int q = 0; q < 4; ++q) {
            short8 s;
#pragma unroll
            for (int e = 0; e < 8; ++e) s[e] = (short)ob[q * 8 + e];
            dst[q] = s;
        }
    }
#pragma unroll
    for (int n = 0; n < 8; ++n) {
        float a = acc[n];
        for (int off = 32; off; off >>= 1) a += __shfl_down(a, off);
        if ((threadIdx.x & 63) == 0) atomicAdd(&sacc[n], a);
    }
    __syncthreads();
    if (threadIdx.x < 8)
        partial[((size_t)b * 512 + blockIdx.x) * 8 + threadIdx.x] = sacc[threadIdx.x];
}

// ---------- Stage 2: cond reduce + kernel-network MLP + Cayley assembly -----
__global__ __launch_bounds__(128)
void mlpw_kernel(const float* __restrict__ partial,
                 const float* __restrict__ w0, const float* __restrict__ b0,
                 const float* __restrict__ w1, const float* __restrict__ b1,
                 const float* __restrict__ w2, const float* __restrict__ b2,
                 unsigned short* __restrict__ wb, float inv_norm, Tables tb) {
    int bx = blockIdx.x;
    int b = bx / XT;
    int tap = bx % XT;
    int t = threadIdx.x;
    __shared__ float red[16][8];
    __shared__ float feat[2 * NB];
    __shared__ float h1[HID];
    __shared__ float h2[HID];
    __shared__ float wrow[320];
    {   // reduce 489 per-block partials for sample b
        int ch = t & 7, seg = t >> 3;    // seg 0..15
        float s = 0.0f;
        for (int j = seg; j < 489; j += 16)
            s += partial[((size_t)b * 512 + j) * 8 + ch];
        red[seg][ch] = s;
    }
    __syncthreads();
    if (t < 8) {
        float v = 0.0f;
        if (t == 1) v = (float)(tap / 9) - 1.0f;
        else if (t == 2) v = (float)((tap / 3) % 3) - 1.0f;
        else if (t == 3) v = (float)(tap % 3) - 1.0f;
        feat[t] = v;
    } else if (t < 16) {
        float s = 0.0f;
#pragma unroll
        for (int q = 0; q < 16; ++q) s += red[q][t - 8];
        feat[t] = s * inv_norm;
    }
    __syncthreads();
    float s = b0[t];
#pragma unroll
    for (int k = 0; k < 2 * NB; ++k) s += feat[k] * w0[k * HID + t];
    h1[t] = gelu_tanh(s);
    __syncthreads();
    s = b1[t];
    for (int k = 0; k < HID; ++k) s += h1[k] * w1[k * HID + t];
    h2[t] = gelu_tanh(s);
    __syncthreads();
    {
        float o0 = b2[t], o1 = b2[t + 128];
        float o2 = (t < 64) ? b2[t + 256] : 0.0f;
        for (int k = 0; k < HID; ++k) {
            float h = h2[k];
            const float* wr = w2 + (size_t)k * 320;
            o0 += h * wr[t];
            o1 += h * wr[t + 128];
            if (t < 64) o2 += h * wr[t + 256];
        }
        wrow[t] = o0;
        wrow[t + 128] = o1;
        if (t < 64) wrow[t + 256] = o2;
    }
    __syncthreads();
    // assemble: thread t -> m = t>>2 (o*8+bk), 8 c values at cq = t&3
    int m = t >> 2, cq = t & 3;
    int o = m >> 3, bk = m & 7;
    short8 sv;
#pragma unroll
    for (int e = 0; e < 8; ++e) {
        int c = cq * 8 + e;
        int i = c >> 3, bj = c & 7, jk = bj * 8 + bk;
        sv[e] = (short)bf16_rne(tb.sgn[jk] * wrow[o * 80 + i * 20 + tb.pid[jk]]);
    }
    *(short8*)(wb + ((size_t)bx * 32 + m) * 32 + cq * 8) = sv;
}

// ---------- Stage 3: MFMA grouped conv, conflict-free slab LDS --------------
// block: 8x8x4 output tile, 4 waves (one z-slice each); halo 10x10x6.
// LDS: 4 K-slabs (16 B/voxel, slab stride 9632 B) -> 2/bank on every phase.
// W double-buffered in registers per (kz,ky) group of 3 taps.
__global__ __launch_bounds__(256, 4)
void conv_lds(const unsigned short* __restrict__ xb, const unsigned short* __restrict__ wb,
              const float* __restrict__ bias, float* __restrict__ out) {
    __shared__ __align__(16) short lds[3 * SLAB + 4800];   // 38496 B
    int b  = blockIdx.y;
    int bx = blockIdx.x;
    int tx = bx % 6, ty = (bx / 6) % 6, tz = bx / 36;
    int X0 = tx * 8, Y0 = ty * 8, Z0 = tz * 4;
    int tid = threadIdx.x;

    const unsigned short* xbb = xb + (size_t)b * PD3 * 32;
    for (int c = tid; c < 2400; c += 256) {
        int h = c >> 2, sl = c & 3;
        int hz = h / 100, rem = h % 100, hy = rem / 10, hx = rem % 10;
        short8 v = *(const short8*)(xbb +
            ((size_t)(Z0 + hz) * PD2 + (size_t)(Y0 + hy) * PD + (X0 + hx)) * 32 + sl * 8);
        *(short8*)(&lds[sl * SLAB + h * 8]) = v;
    }
    __syncthreads();

    int lane = tid & 63, wave = tid >> 6;
    int col = lane & 15, kl = lane >> 4;
    const short* lbase = &lds[kl * SLAB + (wave * 100 + (col >> 3) * 10 + (col & 7)) * 8];
    const unsigned short* wbw = wb + (((size_t)b * XT) * 32 + col) * 32 + kl * 8;

    f32x4 acc[2][4];
#pragma unroll
    for (int mh = 0; mh < 2; ++mh)
#pragma unroll
        for (int r = 0; r < 4; ++r)
#pragma unroll
            for (int e = 0; e < 4; ++e) acc[mh][r][e] = 0.0f;

    short8 wc0[3], wc1[3];
#pragma unroll
    for (int kx = 0; kx < 3; ++kx) {
        wc0[kx] = *(const short8*)(wbw + (size_t)kx * 1024);
        wc1[kx] = *(const short8*)(wbw + (size_t)kx * 1024 + 512);
    }
#pragma unroll
    for (int g = 0; g < 9; ++g) {         // g = kz*3 + ky
        const int kz = g / 3, ky = g % 3;
        short8 wn0[3], wn1[3];
        if (g < 8) {
#pragma unroll
            for (int kx = 0; kx < 3; ++kx) {
                wn0[kx] = *(const short8*)(wbw + (size_t)((g + 1) * 3 + kx) * 1024);
                wn1[kx] = *(const short8*)(wbw + (size_t)((g + 1) * 3 + kx) * 1024 + 512);
            }
        }
#pragma unroll
        for (int kx = 0; kx < 3; ++kx) {
            const int toff = (kz * 100 + ky * 10 + kx) * 8;
#pragma unroll
            for (int r = 0; r < 4; ++r) {
                short8 bf = *(const short8*)(lbase + toff + r * 160);
                acc[0][r] = __builtin_amdgcn_mfma_f32_16x16x32_bf16(wc0[kx], bf, acc[0][r], 0, 0, 0);
                acc[1][r] = __builtin_amdgcn_mfma_f32_16x16x32_bf16(wc1[kx], bf, acc[1][r], 0, 0, 0);
            }
        }
        if (g < 8) {
#pragma unroll
            for (int kx = 0; kx < 3; ++kx) { wc0[kx] = wn0[kx]; wc1[kx] = wn1[kx]; }
        }
    }

    int xc = X0 + (col & 7);
    int z  = Z0 + wave;
#pragma unroll
    for (int mh = 0; mh < 2; ++mh) {
        int m0 = kl * 4 + mh * 16;
        int o = m0 >> 3, bk0 = m0 & 7;
        float bi = (bk0 == 0) ? bias[o] : 0.0f;
#pragma unroll
        for (int r = 0; r < 4; ++r) {
            int y = Y0 + (col >> 3) + 2 * r;
            int vox = (z * 48 + y) * 48 + xc;
            f32x4 v = acc[mh][r];
            v[0] += bi;
            *(f32x4*)(out + (((size_t)(b * 4 + o)) * S3 + vox) * 8 + bk0) = v;
        }
    }
}

// ---------------- host ------------------------------------------------------
static inline int pc_host(int v) { return __builtin_popcount(v); }

extern "C" void kernel_launch(void* const* d_in, const int* in_sizes, int n_in,
                              void* d_out, int out_size, void* d_ws, size_t ws_size,
                              hipStream_t stream) {
    const float* x    = (const float*)d_in[0];
    const float* w0   = (const float*)d_in[1];
    const float* b0   = (const float*)d_in[2];
    const float* w1   = (const float*)d_in[3];
    const float* b1   = (const float*)d_in[4];
    const float* w2   = (const float*)d_in[5];
    const float* b2   = (const float*)d_in[6];
    const float* bias = (const float*)d_in[7];
    float* out = (float*)d_out;

    float* ws      = (float*)d_ws;
    float* partial = ws;                                     // 4*512*8 = 16384 floats
    unsigned short* wbb = (unsigned short*)(ws + 16384);     // bf16 W, 110592 shorts
    unsigned short* xb  = wbb + 110592;                      // padded bf16 x, 32 MB

    // circular-mask voxel count (exact integer arithmetic)
    int cnt = 0;
    for (int z = 0; z < SS; ++z) {
        int dz = 2 * z - 47;
        for (int y = 0; y < SS; ++y) {
            int dy = 2 * y - 47;
            for (int xx = 0; xx < SS; ++xx) {
                int dx = 2 * xx - 47;
                if (dx * dx + dy * dy + dz * dz <= 2209) ++cnt;
            }
        }
    }
    float inv_norm = 1.0f / ((float)cnt * (float)CIN);

    // Cayley sign/path tables
    int pidtab[4][4][4];
    {
        bool ex[4][4][4] = {};
        for (int A = 0; A < 8; ++A)
            for (int B = 0; B < 8; ++B)
                ex[pc_host(A)][pc_host(B)][pc_host(A ^ B)] = true;
        int p = 0;
        for (int gi = 0; gi < 4; ++gi)
            for (int gj = 0; gj < 4; ++gj)
                for (int gk = 0; gk < 4; ++gk)
                    pidtab[gi][gj][gk] = ex[gi][gj][gk] ? p++ : -1;
    }
    static const int blades[8] = {0, 1, 2, 4, 3, 5, 6, 7};  // sorted by (grade, bitmask)
    Tables tb;
    for (int bj = 0; bj < 8; ++bj) {
        for (int bk = 0; bk < 8; ++bk) {
            int bmj = blades[bj], bmk = blades[bk];
            int bma = bmj ^ bmk;
            int sgn = 1, t = bma >> 1;
            while (t) {
                if (pc_host(t & bmj) & 1) sgn = -sgn;
                t >>= 1;
            }
            tb.sgn[bj * 8 + bk] = (float)sgn;
            tb.pid[bj * 8 + bk] = pidtab[pc_host(bma)][pc_host(bmj)][pc_host(bmk)];
        }
    }

    pack_cond_kernel<<<dim3(489, BATCH), dim3(256), 0, stream>>>(x, xb, partial);
    mlpw_kernel<<<dim3(BATCH * XT), dim3(HID), 0, stream>>>(partial, w0, b0, w1, b1, w2, b2,
                                                            wbb, inv_norm, tb);
    conv_lds<<<dim3(432, BATCH), dim3(256), 0, stream>>>(xb, wbb, bias, out);
}

// Round 6
// 92.757 us; speedup vs baseline: 1.2925x; 1.2351x over previous
//
#include <hip/hip_runtime.h>
#include <cmath>

#define SS 48
#define S3 110592
#define NB 8
#define CIN 4
#define COUT 4
#define HID 128
#define XT 27
#define NP 20
#define BATCH 4
#define PD 50
#define PD2 2500
#define PD3 125000
#define SLAB 4816         // shorts per kl-slab (9632 B; ≡ 8 dwords mod 32 banks)

typedef __attribute__((ext_vector_type(8))) short short8;
typedef __attribute__((ext_vector_type(4))) float f32x4;

struct Tables {
    int   pid[64];   // [bj*8+bk] -> path index
    float sgn[64];   // [bj*8+bk] -> +-1
};

__device__ __forceinline__ unsigned short bf16_rne(float f) {
    union { float f; unsigned u; } c; c.f = f;
    unsigned r = c.u + 0x7FFF + ((c.u >> 16) & 1);
    return (unsigned short)(r >> 16);
}

__device__ __forceinline__ float gelu_tanh(float v) {
    const float c = 0.7978845608028654f;   // sqrt(2/pi)
    float u = c * (v + 0.044715f * v * v * v);
    return 0.5f * v * (1.0f + tanhf(u));
}

// ---------- Stage 1: pack x -> padded bf16 [b][pz][py][px][c] + cond partials
__global__ __launch_bounds__(256)
void pack_cond_kernel(const float* __restrict__ x, unsigned short* __restrict__ xb,
                      float* __restrict__ partial) {
    int b  = blockIdx.y;
    int pv = blockIdx.x * 256 + threadIdx.x;
    __shared__ float sacc[8];
    if (threadIdx.x < 8) sacc[threadIdx.x] = 0.0f;
    __syncthreads();
    float acc[8];
#pragma unroll
    for (int n = 0; n < 8; ++n) acc[n] = 0.0f;
    if (pv < PD3) {
        int zp = pv / PD2, rem = pv % PD2, yp = rem / PD, xp = rem % PD;
        int z = zp - 1, y = yp - 1, xx = xp - 1;
        unsigned short ob[32];
        bool interior = (unsigned)z < 48u && (unsigned)y < 48u && (unsigned)xx < 48u;
        if (interior) {
            int v = (z * 48 + y) * 48 + xx;
            float vals[32];
#pragma unroll
            for (int i = 0; i < 4; ++i) {
                const f32x4* p = (const f32x4*)(x + (((size_t)(b * 4 + i)) * S3 + v) * 8);
                f32x4 a = p[0], c4 = p[1];
                vals[i * 8 + 0] = a[0];  vals[i * 8 + 1] = a[1];
                vals[i * 8 + 2] = a[2];  vals[i * 8 + 3] = a[3];
                vals[i * 8 + 4] = c4[0]; vals[i * 8 + 5] = c4[1];
                vals[i * 8 + 6] = c4[2]; vals[i * 8 + 7] = c4[3];
            }
            int dx = 2 * xx - 47, dy = 2 * y - 47, dz = 2 * z - 47;
            if (dx * dx + dy * dy + dz * dz <= 2209) {
#pragma unroll
                for (int n = 0; n < 8; ++n)
                    acc[n] = vals[n] + vals[8 + n] + vals[16 + n] + vals[24 + n];
            }
#pragma unroll
            for (int k = 0; k < 32; ++k) ob[k] = bf16_rne(vals[k]);
        } else {
#pragma unroll
            for (int k = 0; k < 32; ++k) ob[k] = 0;
        }
        short8* dst = (short8*)(xb + ((size_t)b * PD3 + pv) * 32);
#pragma unroll
        for (int q = 0; q < 4; ++q) {
            short8 s;
#pragma unroll
            for (int e = 0; e < 8; ++e) s[e] = (short)ob[q * 8 + e];
            dst[q] = s;
        }
    }
#pragma unroll
    for (int n = 0; n < 8; ++n) {
        float a = acc[n];
        for (int off = 32; off; off >>= 1) a += __shfl_down(a, off);
        if ((threadIdx.x & 63) == 0) atomicAdd(&sacc[n], a);
    }
    __syncthreads();
    if (threadIdx.x < 8)
        partial[((size_t)b * 512 + blockIdx.x) * 8 + threadIdx.x] = sacc[threadIdx.x];
}

// ---------- Stage 2: cond reduce + MLP + Cayley assembly (LDS-staged) -------
// one block per (b, tap); 256 threads; all weight reads staged via LDS.
__global__ __launch_bounds__(256)
void mlpw_kernel(const float* __restrict__ partial,
                 const float* __restrict__ w0, const float* __restrict__ b0,
                 const float* __restrict__ w1, const float* __restrict__ b1,
                 const float* __restrict__ w2, const float* __restrict__ b2,
                 unsigned short* __restrict__ wb, float inv_norm, Tables tb) {
    int bx = blockIdx.x;
    int b = bx / XT;
    int tap = bx % XT;
    int t = threadIdx.x;
    __shared__ float sbuf[10240];      // 40 KB weight staging (reused per phase)
    __shared__ float red[32][8];
    __shared__ float feat[16];
    __shared__ float h1[HID];
    __shared__ float h2[HID];
    __shared__ float wrow[320];

    // Phase 0: reduce 489 per-block partials; stage w0 concurrently
    {
        int ch = t & 7, seg = t >> 3;    // 32 segs
        float s = 0.0f;
        for (int j = seg; j < 489; j += 32)
            s += partial[((size_t)b * 512 + j) * 8 + ch];
        red[seg][ch] = s;
    }
    {
        const f32x4* src = (const f32x4*)w0;
        f32x4* dst = (f32x4*)sbuf;
        for (int j = t; j < 512; j += 256) dst[j] = src[j];
    }
    __syncthreads();
    if (t < 8) {
        float s = 0.0f;
#pragma unroll
        for (int q = 0; q < 32; ++q) s += red[q][t];
        feat[8 + t] = s * inv_norm;
        float v = 0.0f;
        if (t == 1) v = (float)(tap / 9) - 1.0f;
        else if (t == 2) v = (float)((tap / 3) % 3) - 1.0f;
        else if (t == 3) v = (float)(tap % 3) - 1.0f;
        feat[t] = v;
    }
    __syncthreads();

    // Phase 1: feat(16) @ w0 -> h1(128)
    if (t < 128) {
        float s = b0[t];
#pragma unroll
        for (int k = 0; k < 16; ++k) s += feat[k] * sbuf[k * 128 + t];
        h1[t] = gelu_tanh(s);
    }

    // Phase 2: h1 @ w1(128x128) -> h2, staged in 2 chunks of 64 rows (32 KB)
    float s2 = (t < 128) ? b1[t] : 0.0f;
    for (int c = 0; c < 2; ++c) {
        __syncthreads();
        const f32x4* src = (const f32x4*)(w1 + c * 64 * 128);
        f32x4* dst = (f32x4*)sbuf;
        for (int j = t; j < 2048; j += 256) dst[j] = src[j];
        __syncthreads();
        if (t < 128) {
#pragma unroll
            for (int k = 0; k < 64; ++k) s2 += h1[c * 64 + k] * sbuf[k * 128 + t];
        }
    }
    if (t < 128) h2[t] = gelu_tanh(s2);

    // Phase 3: h2 @ w2(128x320) -> wrow(320), staged in 4 chunks of 32 rows (40 KB)
    float oA = b2[t];
    float oB = (t < 64) ? b2[t + 256] : 0.0f;
    for (int c = 0; c < 4; ++c) {
        __syncthreads();
        const f32x4* src = (const f32x4*)(w2 + c * 32 * 320);
        f32x4* dst = (f32x4*)sbuf;
        for (int j = t; j < 2560; j += 256) dst[j] = src[j];
        __syncthreads();
#pragma unroll
        for (int k = 0; k < 32; ++k) {
            float h = h2[c * 32 + k];
            oA += h * sbuf[k * 320 + t];
            if (t < 64) oB += h * sbuf[k * 320 + t + 256];
        }
    }
    wrow[t] = oA;
    if (t < 64) wrow[t + 256] = oB;
    __syncthreads();

    // Phase 4: assemble bf16 W tile [m=o*8+bk][c=i*8+bj]
    if (t < 128) {
        int m = t >> 2, cq = t & 3;
        int o = m >> 3, bk = m & 7;
        short8 sv;
#pragma unroll
        for (int e = 0; e < 8; ++e) {
            int c = cq * 8 + e;
            int i = c >> 3, bj = c & 7, jk = bj * 8 + bk;
            sv[e] = (short)bf16_rne(tb.sgn[jk] * wrow[o * 80 + i * 20 + tb.pid[jk]]);
        }
        *(short8*)(wb + ((size_t)bx * 32 + m) * 32 + cq * 8) = sv;
    }
}

// ---------- Stage 3: MFMA grouped conv, conflict-free slab LDS --------------
// block: 8x8x4 output tile, 4 waves (one z-slice each); halo 10x10x6.
// LDS: 4 K-slabs (16 B/voxel, slab stride 9632 B) -> 2/bank on every phase.
// W double-buffered in registers per (kz,ky) group of 3 taps.
__global__ __launch_bounds__(256, 4)
void conv_lds(const unsigned short* __restrict__ xb, const unsigned short* __restrict__ wb,
              const float* __restrict__ bias, float* __restrict__ out) {
    __shared__ __align__(16) short lds[3 * SLAB + 4800];   // 38496 B
    int b  = blockIdx.y;
    int bx = blockIdx.x;
    int tx = bx % 6, ty = (bx / 6) % 6, tz = bx / 36;
    int X0 = tx * 8, Y0 = ty * 8, Z0 = tz * 4;
    int tid = threadIdx.x;

    const unsigned short* xbb = xb + (size_t)b * PD3 * 32;
    for (int c = tid; c < 2400; c += 256) {
        int h = c >> 2, sl = c & 3;
        int hz = h / 100, rem = h % 100, hy = rem / 10, hx = rem % 10;
        short8 v = *(const short8*)(xbb +
            ((size_t)(Z0 + hz) * PD2 + (size_t)(Y0 + hy) * PD + (X0 + hx)) * 32 + sl * 8);
        *(short8*)(&lds[sl * SLAB + h * 8]) = v;
    }
    __syncthreads();

    int lane = tid & 63, wave = tid >> 6;
    int col = lane & 15, kl = lane >> 4;
    const short* lbase = &lds[kl * SLAB + (wave * 100 + (col >> 3) * 10 + (col & 7)) * 8];
    const unsigned short* wbw = wb + (((size_t)b * XT) * 32 + col) * 32 + kl * 8;

    f32x4 acc[2][4];
#pragma unroll
    for (int mh = 0; mh < 2; ++mh)
#pragma unroll
        for (int r = 0; r < 4; ++r)
#pragma unroll
            for (int e = 0; e < 4; ++e) acc[mh][r][e] = 0.0f;

    short8 wc0[3], wc1[3];
#pragma unroll
    for (int kx = 0; kx < 3; ++kx) {
        wc0[kx] = *(const short8*)(wbw + (size_t)kx * 1024);
        wc1[kx] = *(const short8*)(wbw + (size_t)kx * 1024 + 512);
    }
#pragma unroll
    for (int g = 0; g < 9; ++g) {         // g = kz*3 + ky
        const int kz = g / 3, ky = g % 3;
        short8 wn0[3], wn1[3];
        if (g < 8) {
#pragma unroll
            for (int kx = 0; kx < 3; ++kx) {
                wn0[kx] = *(const short8*)(wbw + (size_t)((g + 1) * 3 + kx) * 1024);
                wn1[kx] = *(const short8*)(wbw + (size_t)((g + 1) * 3 + kx) * 1024 + 512);
            }
        }
#pragma unroll
        for (int kx = 0; kx < 3; ++kx) {
            const int toff = (kz * 100 + ky * 10 + kx) * 8;
#pragma unroll
            for (int r = 0; r < 4; ++r) {
                short8 bf = *(const short8*)(lbase + toff + r * 160);
                acc[0][r] = __builtin_amdgcn_mfma_f32_16x16x32_bf16(wc0[kx], bf, acc[0][r], 0, 0, 0);
                acc[1][r] = __builtin_amdgcn_mfma_f32_16x16x32_bf16(wc1[kx], bf, acc[1][r], 0, 0, 0);
            }
        }
        if (g < 8) {
#pragma unroll
            for (int kx = 0; kx < 3; ++kx) { wc0[kx] = wn0[kx]; wc1[kx] = wn1[kx]; }
        }
    }

    int xc = X0 + (col & 7);
    int z  = Z0 + wave;
#pragma unroll
    for (int mh = 0; mh < 2; ++mh) {
        int m0 = kl * 4 + mh * 16;
        int o = m0 >> 3, bk0 = m0 & 7;
        float bi = (bk0 == 0) ? bias[o] : 0.0f;
#pragma unroll
        for (int r = 0; r < 4; ++r) {
            int y = Y0 + (col >> 3) + 2 * r;
            int vox = (z * 48 + y) * 48 + xc;
            f32x4 v = acc[mh][r];
            v[0] += bi;
            *(f32x4*)(out + (((size_t)(b * 4 + o)) * S3 + vox) * 8 + bk0) = v;
        }
    }
}

// ---------------- host ------------------------------------------------------
static inline int pc_host(int v) { return __builtin_popcount(v); }

extern "C" void kernel_launch(void* const* d_in, const int* in_sizes, int n_in,
                              void* d_out, int out_size, void* d_ws, size_t ws_size,
                              hipStream_t stream) {
    const float* x    = (const float*)d_in[0];
    const float* w0   = (const float*)d_in[1];
    const float* b0   = (const float*)d_in[2];
    const float* w1   = (const float*)d_in[3];
    const float* b1   = (const float*)d_in[4];
    const float* w2   = (const float*)d_in[5];
    const float* b2   = (const float*)d_in[6];
    const float* bias = (const float*)d_in[7];
    float* out = (float*)d_out;

    float* ws      = (float*)d_ws;
    float* partial = ws;                                     // 4*512*8 = 16384 floats
    unsigned short* wbb = (unsigned short*)(ws + 16384);     // bf16 W, 110592 shorts
    unsigned short* xb  = wbb + 110592;                      // padded bf16 x, 32 MB

    // circular-mask voxel count (exact integer arithmetic)
    int cnt = 0;
    for (int z = 0; z < SS; ++z) {
        int dz = 2 * z - 47;
        for (int y = 0; y < SS; ++y) {
            int dy = 2 * y - 47;
            for (int xx = 0; xx < SS; ++xx) {
                int dx = 2 * xx - 47;
                if (dx * dx + dy * dy + dz * dz <= 2209) ++cnt;
            }
        }
    }
    float inv_norm = 1.0f / ((float)cnt * (float)CIN);

    // Cayley sign/path tables
    int pidtab[4][4][4];
    {
        bool ex[4][4][4] = {};
        for (int A = 0; A < 8; ++A)
            for (int B = 0; B < 8; ++B)
                ex[pc_host(A)][pc_host(B)][pc_host(A ^ B)] = true;
        int p = 0;
        for (int gi = 0; gi < 4; ++gi)
            for (int gj = 0; gj < 4; ++gj)
                for (int gk = 0; gk < 4; ++gk)
                    pidtab[gi][gj][gk] = ex[gi][gj][gk] ? p++ : -1;
    }
    static const int blades[8] = {0, 1, 2, 4, 3, 5, 6, 7};  // sorted by (grade, bitmask)
    Tables tb;
    for (int bj = 0; bj < 8; ++bj) {
        for (int bk = 0; bk < 8; ++bk) {
            int bmj = blades[bj], bmk = blades[bk];
            int bma = bmj ^ bmk;
            int sgn = 1, t = bma >> 1;
            while (t) {
                if (pc_host(t & bmj) & 1) sgn = -sgn;
                t >>= 1;
            }
            tb.sgn[bj * 8 + bk] = (float)sgn;
            tb.pid[bj * 8 + bk] = pidtab[pc_host(bma)][pc_host(bmj)][pc_host(bmk)];
        }
    }

    pack_cond_kernel<<<dim3(489, BATCH), dim3(256), 0, stream>>>(x, xb, partial);
    mlpw_kernel<<<dim3(BATCH * XT), dim3(256), 0, stream>>>(partial, w0, b0, w1, b1, w2, b2,
                                                            wbb, inv_norm, tb);
    conv_lds<<<dim3(432, BATCH), dim3(256), 0, stream>>>(xb, wbb, bias, out);
}